// Round 1
// baseline (428.008 us; speedup 1.0000x reference)
//
#include <hip/hip_runtime.h>

typedef __bf16 bf16;
typedef __bf16 bf16x8 __attribute__((ext_vector_type(8)));
typedef float  f32x4  __attribute__((ext_vector_type(4)));

#define MFMA16(a,b,c) __builtin_amdgcn_mfma_f32_16x16x32_bf16((a),(b),(c),0,0,0)

// ---- constants: B=4, S=2048, D=512, H=8, hd=64 ----
#define BATCH 4
#define SEQ   2048
#define DIM   512
#define NH    8
#define HD    64
#define SCALE 0.125f

// swizzled LDS tile: [row][64] bf16, 8-elem units XOR'd by (row&7) -> <=2-way banks
__device__ __forceinline__ bf16x8 ldsfrag(const bf16* t, int row, int kc, int quad){
    int unit = ((kc << 2) + quad) ^ (row & 7);
    return *(const bf16x8*)(t + row * 64 + unit * 8);
}

__device__ __forceinline__ void stage64x64(const bf16* src, long rowStride, bf16* dst, int tid){
#pragma unroll
    for (int rnd = 0; rnd < 2; ++rnd){
        int sid = tid + rnd * 256;          // 512 segs of 8 bf16
        int row = sid >> 3, s = sid & 7;
        bf16x8 val = *(const bf16x8*)(src + (long)row * rowStride + s * 8);
        *(bf16x8*)(dst + row * 64 + ((s ^ (row & 7)) << 3)) = val;
    }
}

// ---------------- kernel 0a: x f32 -> bf16 ----------------
__global__ __launch_bounds__(256) void cvt_x(const float* __restrict__ x, bf16* __restrict__ xb){
    int i = blockIdx.x * 256 + threadIdx.x;          // 4194304/4 threads
    float4 f = ((const float4*)x)[i];
    bf16* o = xb + 4 * (long)i;
    o[0] = (bf16)f.x; o[1] = (bf16)f.y; o[2] = (bf16)f.z; o[3] = (bf16)f.w;
}

// ---------------- kernel 0b: W f32 [k][n] -> WT bf16 [n][k] ----------------
__global__ __launch_bounds__(256) void cvt_wt(const float* __restrict__ Wq, const float* __restrict__ Wk,
                                              const float* __restrict__ Wv, const float* __restrict__ Wo,
                                              bf16* __restrict__ WTb){
    int z = blockIdx.z;
    const float* W = (z == 0) ? Wq : (z == 1) ? Wk : (z == 2) ? Wv : Wo;
    bf16* WT = WTb + (long)z * DIM * DIM;
    __shared__ float lt[32 * 33];
    int t = threadIdx.x, r0 = t >> 5, c = t & 31;
    int k0 = blockIdx.x * 32, n0 = blockIdx.y * 32;
#pragma unroll
    for (int i = 0; i < 4; ++i){
        int row = r0 + i * 8;
        lt[row * 33 + c] = W[(long)(k0 + row) * DIM + n0 + c];
    }
    __syncthreads();
#pragma unroll
    for (int i = 0; i < 4; ++i){
        int nr = r0 + i * 8;
        WT[(long)(n0 + nr) * DIM + k0 + c] = (bf16)lt[c * 33 + nr];
    }
}

// ---------------- kernel 1: QKV projection GEMM ----------------
// Y[m][n] = sum_k X[m][k]*W[k][n] + b[n]; out layout [B,H,S,hd] bf16. z picks q/k/v.
__global__ __launch_bounds__(256) void gemm_qkv(const bf16* __restrict__ X, const bf16* __restrict__ WTb,
                                                const float* __restrict__ bq, const float* __restrict__ bk,
                                                const float* __restrict__ bv, bf16* __restrict__ outb){
    __shared__ __align__(16) bf16 lA[128 * 64];
    __shared__ __align__(16) bf16 lB[128 * 64];
    int z = blockIdx.z;
    const bf16* WT = WTb + (long)z * DIM * DIM;
    const float* bias = (z == 0) ? bq : (z == 1) ? bk : bv;
    bf16* out = outb + (long)z * BATCH * SEQ * DIM;
    int tid = threadIdx.x, lane = tid & 63, w = tid >> 6;
    int wm = w >> 1, wn = w & 1;
    int m0 = blockIdx.y * 128, n0 = blockIdx.x * 128;
    int r16 = lane & 15, quad = lane >> 4;
    f32x4 zz = {0.f, 0.f, 0.f, 0.f};
    f32x4 acc[4][4];
#pragma unroll
    for (int a = 0; a < 4; ++a)
#pragma unroll
        for (int b2 = 0; b2 < 4; ++b2) acc[a][b2] = zz;

    for (int k0 = 0; k0 < DIM; k0 += 64){
        __syncthreads();
#pragma unroll
        for (int rnd = 0; rnd < 4; ++rnd){
            int sid = tid + rnd * 256;       // 1024 segs per tile
            int row = sid >> 3, s = sid & 7;
            *(bf16x8*)(lA + row * 64 + ((s ^ (row & 7)) << 3)) =
                *(const bf16x8*)(X + (long)(m0 + row) * DIM + k0 + s * 8);
            *(bf16x8*)(lB + row * 64 + ((s ^ (row & 7)) << 3)) =
                *(const bf16x8*)(WT + (long)(n0 + row) * DIM + k0 + s * 8);
        }
        __syncthreads();
#pragma unroll
        for (int kc = 0; kc < 2; ++kc){
            bf16x8 aF[4], bF[4];
#pragma unroll
            for (int i = 0; i < 4; ++i){
                aF[i] = ldsfrag(lA, wm * 64 + i * 16 + r16, kc, quad);
                bF[i] = ldsfrag(lB, wn * 64 + i * 16 + r16, kc, quad);
            }
#pragma unroll
            for (int rb = 0; rb < 4; ++rb)
#pragma unroll
                for (int nb = 0; nb < 4; ++nb)
                    acc[rb][nb] = MFMA16(aF[rb], bF[nb], acc[rb][nb]);
        }
    }
#pragma unroll
    for (int nb = 0; nb < 4; ++nb){
        int col = n0 + wn * 64 + nb * 16 + r16;
        float bv_ = bias[col];
        int hh = col >> 6, d = col & 63;
#pragma unroll
        for (int rb = 0; rb < 4; ++rb)
#pragma unroll
            for (int r = 0; r < 4; ++r){
                int row = m0 + wm * 64 + rb * 16 + quad * 4 + r;
                int bb = row >> 11, s = row & 2047;
                out[((long)(bb * NH + hh) * SEQ + s) * HD + d] = (bf16)(acc[rb][nb][r] + bv_);
            }
    }
}

// ---------------- kernel 1.5: v [B,H,S,hd] -> vT [B,H,hd,S] ----------------
__global__ __launch_bounds__(256) void vtrans(const bf16* __restrict__ v, bf16* __restrict__ vT){
    __shared__ bf16 lt[64 * 72];
    int tid = threadIdx.x;
    int s0 = blockIdx.x * 64;
    int bh = blockIdx.z * NH + blockIdx.y;
#pragma unroll
    for (int rnd = 0; rnd < 2; ++rnd){
        int sid = tid + rnd * 256;
        int row = sid >> 3, sg = sid & 7;
        *(bf16x8*)(lt + row * 72 + sg * 8) =
            *(const bf16x8*)(v + ((long)bh * SEQ + s0 + row) * HD + sg * 8);
    }
    __syncthreads();
#pragma unroll
    for (int rnd = 0; rnd < 2; ++rnd){
        int sid = tid + rnd * 256;
        int d = sid >> 3, sg = sid & 7;
        bf16x8 o;
#pragma unroll
        for (int j = 0; j < 8; ++j) o[j] = lt[(sg * 8 + j) * 72 + d];
        *(bf16x8*)(vT + ((long)bh * HD + d) * SEQ + s0 + sg * 8) = o;
    }
}

// ---------------- kernel 2: flash attention (no-max softmax) ----------------
// block = (qtile64, h, b); wave owns 16 q rows. ctx bf16 [B,S,D]; linv f32 [B,H,S].
__global__ __launch_bounds__(256) void attn_flash(const bf16* __restrict__ q, const bf16* __restrict__ k,
                                                  const bf16* __restrict__ vT, bf16* __restrict__ ctx,
                                                  float* __restrict__ linv_g){
    __shared__ __align__(16) bf16 lQ[64 * 64];
    __shared__ __align__(16) bf16 lK[64 * 64];
    __shared__ __align__(16) bf16 lV[64 * 64];
    __shared__ __align__(16) bf16 lP[4][16 * 64];
    int tid = threadIdx.x, lane = tid & 63, w = tid >> 6;
    int h = blockIdx.y, b = blockIdx.z;
    int bh = b * NH + h;
    int q0 = blockIdx.x * 64;
    int r16 = lane & 15, quad = lane >> 4;

    stage64x64(q + ((long)bh * SEQ + q0) * HD, HD, lQ, tid);
    __syncthreads();
    bf16x8 aF0 = ldsfrag(lQ, w * 16 + r16, 0, quad);
    bf16x8 aF1 = ldsfrag(lQ, w * 16 + r16, 1, quad);

    f32x4 zz = {0.f, 0.f, 0.f, 0.f};
    f32x4 ctxacc[4];
    float lsum[4] = {0.f, 0.f, 0.f, 0.f};
#pragma unroll
    for (int cb = 0; cb < 4; ++cb) ctxacc[cb] = zz;

    for (int j0 = 0; j0 < SEQ; j0 += 64){
        __syncthreads();
        stage64x64(k + ((long)bh * SEQ + j0) * HD, HD, lK, tid);
        stage64x64(vT + (long)bh * HD * SEQ + j0, SEQ, lV, tid);
        __syncthreads();
        // QK^T -> p (exp, unnormalized), accumulate row sums, stash p in LDS (A-layout src)
#pragma unroll
        for (int cb = 0; cb < 4; ++cb){
            f32x4 sa = zz;
            sa = MFMA16(aF0, ldsfrag(lK, cb * 16 + r16, 0, quad), sa);
            sa = MFMA16(aF1, ldsfrag(lK, cb * 16 + r16, 1, quad), sa);
#pragma unroll
            for (int r = 0; r < 4; ++r){
                float p = __expf(sa[r] * SCALE);
                lsum[r] += p;
                int row = quad * 4 + r, col = cb * 16 + r16;
                int unit = (col >> 3) ^ (row & 7);
                lP[w][row * 64 + unit * 8 + (col & 7)] = (bf16)p;
            }
        }
        __syncthreads();
        // PV
#pragma unroll
        for (int kc = 0; kc < 2; ++kc){
            bf16x8 pF = ldsfrag(lP[w], r16, kc, quad);
#pragma unroll
            for (int cb = 0; cb < 4; ++cb)
                ctxacc[cb] = MFMA16(pF, ldsfrag(lV, cb * 16 + r16, kc, quad), ctxacc[cb]);
        }
    }
    // reduce row sums over the 16 lanes holding the same rows
#pragma unroll
    for (int m = 1; m < 16; m <<= 1)
#pragma unroll
        for (int r = 0; r < 4; ++r) lsum[r] += __shfl_xor(lsum[r], m, 64);
    float rinv[4];
#pragma unroll
    for (int r = 0; r < 4; ++r) rinv[r] = 1.0f / lsum[r];
#pragma unroll
    for (int cb = 0; cb < 4; ++cb)
#pragma unroll
        for (int r = 0; r < 4; ++r){
            long srow = q0 + w * 16 + quad * 4 + r;
            ctx[((long)b * SEQ + srow) * DIM + h * HD + cb * 16 + r16] = (bf16)(ctxacc[cb][r] * rinv[r]);
        }
    if (r16 == 0)
#pragma unroll
        for (int r = 0; r < 4; ++r)
            linv_g[(long)bh * SEQ + q0 + w * 16 + quad * 4 + r] = rinv[r];
}

// ---------------- kernel 3: avg_attn (recompute scores, all 8 heads per block) ----
// block = (qtile32, b); wave: rb = w&1 (16 rows), hg = w>>1 (4 heads). lP aliases lK.
__global__ __launch_bounds__(256) void attn_avg(const bf16* __restrict__ q, const bf16* __restrict__ k,
                                                const float* __restrict__ linv_g, float* __restrict__ avg){
    __shared__ __align__(16) bf16 lK[NH * 64 * 64];   // 64 KB
    float* lPf = (float*)lK;                           // 16 KB alias, used after sync
    int tid = threadIdx.x, lane = tid & 63, w = tid >> 6;
    int b = blockIdx.y;
    int q0 = blockIdx.x * 32;
    int rb = w & 1, hg = w >> 1;
    int r16 = lane & 15, quad = lane >> 4;

    bf16x8 aF[4][2];
    float lv[4][4];
#pragma unroll
    for (int hh = 0; hh < 4; ++hh){
        int hA = b * NH + hg * 4 + hh;
        long qbase = ((long)hA * SEQ + q0 + rb * 16 + r16) * HD + quad * 8;
        aF[hh][0] = *(const bf16x8*)(q + qbase);
        aF[hh][1] = *(const bf16x8*)(q + qbase + 32);
#pragma unroll
        for (int r = 0; r < 4; ++r)
            lv[hh][r] = linv_g[(long)hA * SEQ + q0 + rb * 16 + quad * 4 + r];
    }

    for (int j0 = 0; j0 < SEQ; j0 += 64){
        __syncthreads();
#pragma unroll
        for (int rnd = 0; rnd < 16; ++rnd){
            int sid = tid + rnd * 256;            // 4096 segs
            int hkey = sid >> 3, s = sid & 7;
            int hh2 = hkey >> 6, key = hkey & 63;
            bf16x8 val = *(const bf16x8*)(k + ((long)(b * NH + hh2) * SEQ + j0 + key) * HD + s * 8);
            *(bf16x8*)(lK + hkey * 64 + ((s ^ (key & 7)) << 3)) = val;
        }
        __syncthreads();
        float psum[4][4];
#pragma unroll
        for (int cb = 0; cb < 4; ++cb)
#pragma unroll
            for (int r = 0; r < 4; ++r) psum[cb][r] = 0.f;
#pragma unroll
        for (int hh = 0; hh < 4; ++hh){
            const bf16* lKh = lK + (hg * 4 + hh) * 4096;
#pragma unroll
            for (int cb = 0; cb < 4; ++cb){
                f32x4 sa = {0.f, 0.f, 0.f, 0.f};
                sa = MFMA16(aF[hh][0], ldsfrag(lKh, cb * 16 + r16, 0, quad), sa);
                sa = MFMA16(aF[hh][1], ldsfrag(lKh, cb * 16 + r16, 1, quad), sa);
#pragma unroll
                for (int r = 0; r < 4; ++r)
                    psum[cb][r] += __expf(sa[r] * SCALE) * lv[hh][r];
            }
        }
        __syncthreads();   // all waves done reading lK before lPf overwrites it
#pragma unroll
        for (int cb = 0; cb < 4; ++cb)
#pragma unroll
            for (int r = 0; r < 4; ++r)
                lPf[w * 1024 + (quad * 4 + r) * 64 + cb * 16 + r16] = psum[cb][r];
        __syncthreads();
#pragma unroll
        for (int i = 0; i < 8; ++i){
            int idx = tid + i * 256;               // 2048 outputs (32 rows x 64 cols)
            int row = idx >> 6, col = idx & 63;
            int rb2 = row >> 4, rl = row & 15;
            float val = (lPf[rb2 * 1024 + rl * 64 + col] + lPf[(rb2 + 2) * 1024 + rl * 64 + col]) * 0.125f;
            avg[((long)(b * SEQ + q0 + row)) * SEQ + j0 + col] = val;
        }
    }
}

// ---------------- kernel 4: output projection ----------------
__global__ __launch_bounds__(256) void gemm_out(const bf16* __restrict__ CTX, const bf16* __restrict__ WT,
                                                const float* __restrict__ bo, float* __restrict__ out){
    __shared__ __align__(16) bf16 lA[128 * 64];
    __shared__ __align__(16) bf16 lB[128 * 64];
    int tid = threadIdx.x, lane = tid & 63, w = tid >> 6;
    int wm = w >> 1, wn = w & 1;
    int m0 = blockIdx.y * 128, n0 = blockIdx.x * 128;
    int r16 = lane & 15, quad = lane >> 4;
    f32x4 zz = {0.f, 0.f, 0.f, 0.f};
    f32x4 acc[4][4];
#pragma unroll
    for (int a = 0; a < 4; ++a)
#pragma unroll
        for (int b2 = 0; b2 < 4; ++b2) acc[a][b2] = zz;

    for (int k0 = 0; k0 < DIM; k0 += 64){
        __syncthreads();
#pragma unroll
        for (int rnd = 0; rnd < 4; ++rnd){
            int sid = tid + rnd * 256;
            int row = sid >> 3, s = sid & 7;
            *(bf16x8*)(lA + row * 64 + ((s ^ (row & 7)) << 3)) =
                *(const bf16x8*)(CTX + (long)(m0 + row) * DIM + k0 + s * 8);
            *(bf16x8*)(lB + row * 64 + ((s ^ (row & 7)) << 3)) =
                *(const bf16x8*)(WT + (long)(n0 + row) * DIM + k0 + s * 8);
        }
        __syncthreads();
#pragma unroll
        for (int kc = 0; kc < 2; ++kc){
            bf16x8 aF[4], bF[4];
#pragma unroll
            for (int i = 0; i < 4; ++i){
                aF[i] = ldsfrag(lA, wm * 64 + i * 16 + r16, kc, quad);
                bF[i] = ldsfrag(lB, wn * 64 + i * 16 + r16, kc, quad);
            }
#pragma unroll
            for (int rb2 = 0; rb2 < 4; ++rb2)
#pragma unroll
                for (int nb = 0; nb < 4; ++nb)
                    acc[rb2][nb] = MFMA16(aF[rb2], bF[nb], acc[rb2][nb]);
        }
    }
#pragma unroll
    for (int nb = 0; nb < 4; ++nb){
        int col = n0 + wn * 64 + nb * 16 + r16;
        float bv_ = bo[col];
#pragma unroll
        for (int rb2 = 0; rb2 < 4; ++rb2)
#pragma unroll
            for (int r = 0; r < 4; ++r){
                int row = m0 + wm * 64 + rb2 * 16 + quad * 4 + r;
                out[(long)row * DIM + col] = acc[rb2][nb][r] + bv_;
            }
    }
}

extern "C" void kernel_launch(void* const* d_in, const int* in_sizes, int n_in,
                              void* d_out, int out_size, void* d_ws, size_t ws_size,
                              hipStream_t stream) {
    const float* x  = (const float*)d_in[0];
    const float* Wq = (const float*)d_in[1];
    const float* bq = (const float*)d_in[2];
    const float* Wk = (const float*)d_in[3];
    const float* bk = (const float*)d_in[4];
    const float* Wv = (const float*)d_in[5];
    const float* bv = (const float*)d_in[6];
    const float* Wo = (const float*)d_in[7];
    const float* bo = (const float*)d_in[8];
    float* out = (float*)d_out;

    char* ws = (char*)d_ws;
    // ws layout (bytes): xb 8.0MB | WT 2MB | q,k,v 3x8MB | vT 8MB | ctx 8MB | linv 256KB  (~50.3 MB)
    bf16*  xb   = (bf16*)(ws);
    bf16*  WT   = (bf16*)(ws + 8388608);
    bf16*  qb   = (bf16*)(ws + 10485760);
    bf16*  kb   = qb + (long)BATCH * SEQ * DIM;
    bf16*  vb   = kb + (long)BATCH * SEQ * DIM;
    bf16*  vT   = (bf16*)(ws + 35651584);
    bf16*  ctx  = (bf16*)(ws + 44040192);
    float* linv = (float*)(ws + 52428800);

    cvt_x    <<<4096, 256, 0, stream>>>(x, xb);
    cvt_wt   <<<dim3(16, 16, 4), 256, 0, stream>>>(Wq, Wk, Wv, Wo, WT);
    gemm_qkv <<<dim3(4, 64, 3), 256, 0, stream>>>(xb, WT, bq, bk, bv, qb);
    vtrans   <<<dim3(32, 8, 4), 256, 0, stream>>>(vb, vT);
    attn_flash<<<dim3(32, 8, 4), 256, 0, stream>>>(qb, kb, vT, ctx, linv);
    attn_avg <<<dim3(64, 4), 256, 0, stream>>>(qb, kb, linv, out + (long)BATCH * SEQ * DIM);
    gemm_out <<<dim3(4, 64), 256, 0, stream>>>(ctx, WT + 3L * DIM * DIM, bo, out);
}

// Round 2
// 305.449 us; speedup vs baseline: 1.4012x; 1.4012x over previous
//
#include <hip/hip_runtime.h>

typedef __bf16 bf16;
typedef __bf16 bf16x8 __attribute__((ext_vector_type(8)));
typedef float  f32x4  __attribute__((ext_vector_type(4)));

#define MFMA16(a,b,c) __builtin_amdgcn_mfma_f32_16x16x32_bf16((a),(b),(c),0,0,0)

// ---- constants: B=4, S=2048, D=512, H=8, hd=64 ----
#define BATCH 4
#define SEQ   2048
#define DIM   512
#define NH    8
#define HD    64
#define SCALE 0.125f

// swizzled LDS tile: [row][64] bf16, 8-elem units XOR'd by (row&7) -> <=2-way banks
__device__ __forceinline__ bf16x8 ldsfrag(const bf16* t, int row, int kc, int quad){
    int unit = ((kc << 2) + quad) ^ (row & 7);
    return *(const bf16x8*)(t + row * 64 + unit * 8);
}

__device__ __forceinline__ void stage64x64(const bf16* src, long rowStride, bf16* dst, int tid){
#pragma unroll
    for (int rnd = 0; rnd < 2; ++rnd){
        int sid = tid + rnd * 256;          // 512 segs of 8 bf16
        int row = sid >> 3, s = sid & 7;
        bf16x8 val = *(const bf16x8*)(src + (long)row * rowStride + s * 8);
        *(bf16x8*)(dst + row * 64 + ((s ^ (row & 7)) << 3)) = val;
    }
}

// ---------------- kernel 0a: x f32 -> bf16 ----------------
__global__ __launch_bounds__(256) void cvt_x(const float* __restrict__ x, bf16* __restrict__ xb){
    int i = blockIdx.x * 256 + threadIdx.x;          // 4194304/4 threads
    float4 f = ((const float4*)x)[i];
    bf16* o = xb + 4 * (long)i;
    o[0] = (bf16)f.x; o[1] = (bf16)f.y; o[2] = (bf16)f.z; o[3] = (bf16)f.w;
}

// ---------------- kernel 0b: W f32 [k][n] -> WT bf16 [n][k] ----------------
__global__ __launch_bounds__(256) void cvt_wt(const float* __restrict__ Wq, const float* __restrict__ Wk,
                                              const float* __restrict__ Wv, const float* __restrict__ Wo,
                                              bf16* __restrict__ WTb){
    int z = blockIdx.z;
    const float* W = (z == 0) ? Wq : (z == 1) ? Wk : (z == 2) ? Wv : Wo;
    bf16* WT = WTb + (long)z * DIM * DIM;
    __shared__ float lt[32 * 33];
    int t = threadIdx.x, r0 = t >> 5, c = t & 31;
    int k0 = blockIdx.x * 32, n0 = blockIdx.y * 32;
#pragma unroll
    for (int i = 0; i < 4; ++i){
        int row = r0 + i * 8;
        lt[row * 33 + c] = W[(long)(k0 + row) * DIM + n0 + c];
    }
    __syncthreads();
#pragma unroll
    for (int i = 0; i < 4; ++i){
        int nr = r0 + i * 8;
        WT[(long)(n0 + nr) * DIM + k0 + c] = (bf16)lt[c * 33 + nr];
    }
}

// ---------------- kernel 1: QKV projection GEMM ----------------
// Y[m][n] = sum_k X[m][k]*W[k][n] + b[n]; out layout [B,H,S,hd] bf16. z picks q/k/v.
__global__ __launch_bounds__(256) void gemm_qkv(const bf16* __restrict__ X, const bf16* __restrict__ WTb,
                                                const float* __restrict__ bq, const float* __restrict__ bk,
                                                const float* __restrict__ bv, bf16* __restrict__ outb){
    __shared__ __align__(16) bf16 lA[128 * 64];
    __shared__ __align__(16) bf16 lB[128 * 64];
    int z = blockIdx.z;
    const bf16* WT = WTb + (long)z * DIM * DIM;
    const float* bias = (z == 0) ? bq : (z == 1) ? bk : bv;
    bf16* out = outb + (long)z * BATCH * SEQ * DIM;
    int tid = threadIdx.x, lane = tid & 63, w = tid >> 6;
    int wm = w >> 1, wn = w & 1;
    int m0 = blockIdx.y * 128, n0 = blockIdx.x * 128;
    int r16 = lane & 15, quad = lane >> 4;
    f32x4 zz = {0.f, 0.f, 0.f, 0.f};
    f32x4 acc[4][4];
#pragma unroll
    for (int a = 0; a < 4; ++a)
#pragma unroll
        for (int b2 = 0; b2 < 4; ++b2) acc[a][b2] = zz;

    for (int k0 = 0; k0 < DIM; k0 += 64){
        __syncthreads();
#pragma unroll
        for (int rnd = 0; rnd < 4; ++rnd){
            int sid = tid + rnd * 256;       // 1024 segs per tile
            int row = sid >> 3, s = sid & 7;
            *(bf16x8*)(lA + row * 64 + ((s ^ (row & 7)) << 3)) =
                *(const bf16x8*)(X + (long)(m0 + row) * DIM + k0 + s * 8);
            *(bf16x8*)(lB + row * 64 + ((s ^ (row & 7)) << 3)) =
                *(const bf16x8*)(WT + (long)(n0 + row) * DIM + k0 + s * 8);
        }
        __syncthreads();
#pragma unroll
        for (int kc = 0; kc < 2; ++kc){
            bf16x8 aF[4], bF[4];
#pragma unroll
            for (int i = 0; i < 4; ++i){
                aF[i] = ldsfrag(lA, wm * 64 + i * 16 + r16, kc, quad);
                bF[i] = ldsfrag(lB, wn * 64 + i * 16 + r16, kc, quad);
            }
#pragma unroll
            for (int rb = 0; rb < 4; ++rb)
#pragma unroll
                for (int nb = 0; nb < 4; ++nb)
                    acc[rb][nb] = MFMA16(aF[rb], bF[nb], acc[rb][nb]);
        }
    }
#pragma unroll
    for (int nb = 0; nb < 4; ++nb){
        int col = n0 + wn * 64 + nb * 16 + r16;
        float bv_ = bias[col];
        int hh = col >> 6, d = col & 63;
#pragma unroll
        for (int rb = 0; rb < 4; ++rb)
#pragma unroll
            for (int r = 0; r < 4; ++r){
                int row = m0 + wm * 64 + rb * 16 + quad * 4 + r;
                int bb = row >> 11, s = row & 2047;
                out[((long)(bb * NH + hh) * SEQ + s) * HD + d] = (bf16)(acc[rb][nb][r] + bv_);
            }
    }
}

// ---------------- kernel 1.5: v [B,H,S,hd] -> vT [B,H,hd,S] ----------------
__global__ __launch_bounds__(256) void vtrans(const bf16* __restrict__ v, bf16* __restrict__ vT){
    __shared__ bf16 lt[64 * 72];
    int tid = threadIdx.x;
    int s0 = blockIdx.x * 64;
    int bh = blockIdx.z * NH + blockIdx.y;
#pragma unroll
    for (int rnd = 0; rnd < 2; ++rnd){
        int sid = tid + rnd * 256;
        int row = sid >> 3, sg = sid & 7;
        *(bf16x8*)(lt + row * 72 + sg * 8) =
            *(const bf16x8*)(v + ((long)bh * SEQ + s0 + row) * HD + sg * 8);
    }
    __syncthreads();
#pragma unroll
    for (int rnd = 0; rnd < 2; ++rnd){
        int sid = tid + rnd * 256;
        int d = sid >> 3, sg = sid & 7;
        bf16x8 o;
#pragma unroll
        for (int j = 0; j < 8; ++j) o[j] = lt[(sg * 8 + j) * 72 + d];
        *(bf16x8*)(vT + ((long)bh * HD + d) * SEQ + s0 + sg * 8) = o;
    }
}

// ---------------- kernel 2: flash attention (no-max softmax) ----------------
// block = (qtile64, h, b); wave owns 16 q rows. ctx bf16 [B,S,D]; linv f32 [B,H,S].
__global__ __launch_bounds__(256) void attn_flash(const bf16* __restrict__ q, const bf16* __restrict__ k,
                                                  const bf16* __restrict__ vT, bf16* __restrict__ ctx,
                                                  float* __restrict__ linv_g){
    __shared__ __align__(16) bf16 lQ[64 * 64];
    __shared__ __align__(16) bf16 lK[64 * 64];
    __shared__ __align__(16) bf16 lV[64 * 64];
    __shared__ __align__(16) bf16 lP[4][16 * 64];
    int tid = threadIdx.x, lane = tid & 63, w = tid >> 6;
    int h = blockIdx.y, b = blockIdx.z;
    int bh = b * NH + h;
    int q0 = blockIdx.x * 64;
    int r16 = lane & 15, quad = lane >> 4;

    stage64x64(q + ((long)bh * SEQ + q0) * HD, HD, lQ, tid);
    __syncthreads();
    bf16x8 aF0 = ldsfrag(lQ, w * 16 + r16, 0, quad);
    bf16x8 aF1 = ldsfrag(lQ, w * 16 + r16, 1, quad);

    f32x4 zz = {0.f, 0.f, 0.f, 0.f};
    f32x4 ctxacc[4];
    float lsum[4] = {0.f, 0.f, 0.f, 0.f};
#pragma unroll
    for (int cb = 0; cb < 4; ++cb) ctxacc[cb] = zz;

    for (int j0 = 0; j0 < SEQ; j0 += 64){
        __syncthreads();
        stage64x64(k + ((long)bh * SEQ + j0) * HD, HD, lK, tid);
        stage64x64(vT + (long)bh * HD * SEQ + j0, SEQ, lV, tid);
        __syncthreads();
        // QK^T -> p (exp, unnormalized), accumulate row sums, stash p in LDS (A-layout src)
#pragma unroll
        for (int cb = 0; cb < 4; ++cb){
            f32x4 sa = zz;
            sa = MFMA16(aF0, ldsfrag(lK, cb * 16 + r16, 0, quad), sa);
            sa = MFMA16(aF1, ldsfrag(lK, cb * 16 + r16, 1, quad), sa);
#pragma unroll
            for (int r = 0; r < 4; ++r){
                float p = __expf(sa[r] * SCALE);
                lsum[r] += p;
                int row = quad * 4 + r, col = cb * 16 + r16;
                int unit = (col >> 3) ^ (row & 7);
                lP[w][row * 64 + unit * 8 + (col & 7)] = (bf16)p;
            }
        }
        __syncthreads();
        // PV
#pragma unroll
        for (int kc = 0; kc < 2; ++kc){
            bf16x8 pF = ldsfrag(lP[w], r16, kc, quad);
#pragma unroll
            for (int cb = 0; cb < 4; ++cb)
                ctxacc[cb] = MFMA16(pF, ldsfrag(lV, cb * 16 + r16, kc, quad), ctxacc[cb]);
        }
    }
    // reduce row sums over the 16 lanes holding the same rows
#pragma unroll
    for (int m = 1; m < 16; m <<= 1)
#pragma unroll
        for (int r = 0; r < 4; ++r) lsum[r] += __shfl_xor(lsum[r], m, 64);
    float rinv[4];
#pragma unroll
    for (int r = 0; r < 4; ++r) rinv[r] = 1.0f / lsum[r];
#pragma unroll
    for (int cb = 0; cb < 4; ++cb)
#pragma unroll
        for (int r = 0; r < 4; ++r){
            long srow = q0 + w * 16 + quad * 4 + r;
            ctx[((long)b * SEQ + srow) * DIM + h * HD + cb * 16 + r16] = (bf16)(ctxacc[cb][r] * rinv[r]);
        }
    if (r16 == 0)
#pragma unroll
        for (int r = 0; r < 4; ++r)
            linv_g[(long)bh * SEQ + q0 + w * 16 + quad * 4 + r] = rinv[r];
}

// ---------------- kernel 3: avg_attn (recompute scores) ----------------
// grid = (qtile64, jchunk8, b). Wave w owns q-rows q0+w*16..+16 and ALL 8 heads
// (no cross-wave reduction). Each block handles 4 j-tiles of 64 keys.
__global__ __launch_bounds__(256) void attn_avg(const bf16* __restrict__ q, const bf16* __restrict__ k,
                                                const float* __restrict__ linv_g, float* __restrict__ avg){
    __shared__ __align__(16) bf16 lK[NH * 64 * 64];   // 64 KB: 8 heads x 64 keys x 64 hd
    int tid = threadIdx.x, lane = tid & 63, w = tid >> 6;
    int b = blockIdx.z;
    int q0 = blockIdx.x * 64;
    int jc = blockIdx.y;                               // 8 chunks x 256 keys
    int r16 = lane & 15, quad = lane >> 4;

    // A-fragments for 16 q-rows x 8 heads, straight from global (contiguous 16B/lane)
    bf16x8 aF[NH][2];
    float lv[NH][4];
#pragma unroll
    for (int hh = 0; hh < NH; ++hh){
        long hA = (long)b * NH + hh;
        long qbase = (hA * SEQ + q0 + w * 16 + r16) * HD + quad * 8;
        aF[hh][0] = *(const bf16x8*)(q + qbase);
        aF[hh][1] = *(const bf16x8*)(q + qbase + 32);
#pragma unroll
        for (int r = 0; r < 4; ++r)
            lv[hh][r] = linv_g[hA * SEQ + q0 + w * 16 + quad * 4 + r];
    }

#pragma unroll 1
    for (int jt = 0; jt < 4; ++jt){
        int j0 = jc * 256 + jt * 64;
        __syncthreads();                               // guard lK reuse
#pragma unroll
        for (int rnd = 0; rnd < 16; ++rnd){
            int sid = tid + rnd * 256;                 // 4096 segs of 8 bf16
            int hkey = sid >> 3, s = sid & 7;
            int hh2 = hkey >> 6, key = hkey & 63;
            bf16x8 val = *(const bf16x8*)(k + ((long)(b * NH + hh2) * SEQ + j0 + key) * HD + s * 8);
            *(bf16x8*)(lK + hkey * 64 + ((s ^ (key & 7)) << 3)) = val;
        }
        __syncthreads();
        float psum[4][4];
#pragma unroll
        for (int cb = 0; cb < 4; ++cb)
#pragma unroll
            for (int r = 0; r < 4; ++r) psum[cb][r] = 0.f;
#pragma unroll
        for (int hh = 0; hh < NH; ++hh){
            const bf16* lKh = lK + hh * 4096;
#pragma unroll
            for (int cb = 0; cb < 4; ++cb){
                f32x4 sa = {0.f, 0.f, 0.f, 0.f};
                sa = MFMA16(aF[hh][0], ldsfrag(lKh, cb * 16 + r16, 0, quad), sa);
                sa = MFMA16(aF[hh][1], ldsfrag(lKh, cb * 16 + r16, 1, quad), sa);
#pragma unroll
                for (int r = 0; r < 4; ++r)
                    psum[cb][r] += __expf(sa[r] * SCALE) * lv[hh][r];
            }
        }
        // write 16 f32 per lane; 16-lane groups are 64B-contiguous
#pragma unroll
        for (int cb = 0; cb < 4; ++cb)
#pragma unroll
            for (int r = 0; r < 4; ++r)
                avg[((long)(b * SEQ + q0 + w * 16 + quad * 4 + r)) * SEQ + j0 + cb * 16 + r16] =
                    psum[cb][r] * 0.125f;
    }
}

// ---------------- kernel 4: output projection ----------------
__global__ __launch_bounds__(256) void gemm_out(const bf16* __restrict__ CTX, const bf16* __restrict__ WT,
                                                const float* __restrict__ bo, float* __restrict__ out){
    __shared__ __align__(16) bf16 lA[128 * 64];
    __shared__ __align__(16) bf16 lB[128 * 64];
    int tid = threadIdx.x, lane = tid & 63, w = tid >> 6;
    int wm = w >> 1, wn = w & 1;
    int m0 = blockIdx.y * 128, n0 = blockIdx.x * 128;
    int r16 = lane & 15, quad = lane >> 4;
    f32x4 zz = {0.f, 0.f, 0.f, 0.f};
    f32x4 acc[4][4];
#pragma unroll
    for (int a = 0; a < 4; ++a)
#pragma unroll
        for (int b2 = 0; b2 < 4; ++b2) acc[a][b2] = zz;

    for (int k0 = 0; k0 < DIM; k0 += 64){
        __syncthreads();
#pragma unroll
        for (int rnd = 0; rnd < 4; ++rnd){
            int sid = tid + rnd * 256;
            int row = sid >> 3, s = sid & 7;
            *(bf16x8*)(lA + row * 64 + ((s ^ (row & 7)) << 3)) =
                *(const bf16x8*)(CTX + (long)(m0 + row) * DIM + k0 + s * 8);
            *(bf16x8*)(lB + row * 64 + ((s ^ (row & 7)) << 3)) =
                *(const bf16x8*)(WT + (long)(n0 + row) * DIM + k0 + s * 8);
        }
        __syncthreads();
#pragma unroll
        for (int kc = 0; kc < 2; ++kc){
            bf16x8 aF[4], bF[4];
#pragma unroll
            for (int i = 0; i < 4; ++i){
                aF[i] = ldsfrag(lA, wm * 64 + i * 16 + r16, kc, quad);
                bF[i] = ldsfrag(lB, wn * 64 + i * 16 + r16, kc, quad);
            }
#pragma unroll
            for (int rb2 = 0; rb2 < 4; ++rb2)
#pragma unroll
                for (int nb = 0; nb < 4; ++nb)
                    acc[rb2][nb] = MFMA16(aF[rb2], bF[nb], acc[rb2][nb]);
        }
    }
#pragma unroll
    for (int nb = 0; nb < 4; ++nb){
        int col = n0 + wn * 64 + nb * 16 + r16;
        float bv_ = bo[col];
#pragma unroll
        for (int rb2 = 0; rb2 < 4; ++rb2)
#pragma unroll
            for (int r = 0; r < 4; ++r){
                int row = m0 + wm * 64 + rb2 * 16 + quad * 4 + r;
                out[(long)row * DIM + col] = acc[rb2][nb][r] + bv_;
            }
    }
}

extern "C" void kernel_launch(void* const* d_in, const int* in_sizes, int n_in,
                              void* d_out, int out_size, void* d_ws, size_t ws_size,
                              hipStream_t stream) {
    const float* x  = (const float*)d_in[0];
    const float* Wq = (const float*)d_in[1];
    const float* bq = (const float*)d_in[2];
    const float* Wk = (const float*)d_in[3];
    const float* bk = (const float*)d_in[4];
    const float* Wv = (const float*)d_in[5];
    const float* bv = (const float*)d_in[6];
    const float* Wo = (const float*)d_in[7];
    const float* bo = (const float*)d_in[8];
    float* out = (float*)d_out;

    char* ws = (char*)d_ws;
    // ws layout (bytes): xb 8.0MB | WT 2MB | q,k,v 3x8MB | vT 8MB | ctx 8MB | linv 256KB  (~50.3 MB)
    bf16*  xb   = (bf16*)(ws);
    bf16*  WT   = (bf16*)(ws + 8388608);
    bf16*  qb   = (bf16*)(ws + 10485760);
    bf16*  kb   = qb + (long)BATCH * SEQ * DIM;
    bf16*  vb   = kb + (long)BATCH * SEQ * DIM;
    bf16*  vT   = (bf16*)(ws + 35651584);
    bf16*  ctx  = (bf16*)(ws + 44040192);
    float* linv = (float*)(ws + 52428800);

    cvt_x    <<<4096, 256, 0, stream>>>(x, xb);
    cvt_wt   <<<dim3(16, 16, 4), 256, 0, stream>>>(Wq, Wk, Wv, Wo, WT);
    gemm_qkv <<<dim3(4, 64, 3), 256, 0, stream>>>(xb, WT, bq, bk, bv, qb);
    vtrans   <<<dim3(32, 8, 4), 256, 0, stream>>>(vb, vT);
    attn_flash<<<dim3(32, 8, 4), 256, 0, stream>>>(qb, kb, vT, ctx, linv);
    attn_avg <<<dim3(32, 8, 4), 256, 0, stream>>>(qb, kb, linv, out + (long)BATCH * SEQ * DIM);
    gemm_out <<<dim3(4, 64), 256, 0, stream>>>(ctx, WT + 3L * DIM * DIM, bo, out);
}